// Round 8
// baseline (171.475 us; speedup 1.0000x reference)
//
#include <hip/hip_runtime.h>
#include <hip/hip_cooperative_groups.h>
#include <cstdint>

namespace cg = cooperative_groups;

typedef unsigned long long u64;
typedef uint32_t u32;

#define NB 2048
#define EDGE_CAP 16384
#define CLIST_CAP 2048

// ---------------------------------------------------------------------------
// Single cooperative kernel: build -> grid.sync -> cand+geom -> grid.sync ->
// greedy fixpoint + output (block 0). 256 blocks x 256 threads, 1 block/CU.
// All geometry is a faithful f32 replication of the reference (contract(off));
// angle sort uses a diamond pseudo-angle (strictly order-equivalent to atan2)
// and a key-only register bitonic network (static indices -> no scratch).
// ---------------------------------------------------------------------------
__global__ __launch_bounds__(256) void nms_all_kernel(
    const float* __restrict__ boxes, const float* __restrict__ scores,
    const int* __restrict__ labels, const float* __restrict__ thrp,
    float* __restrict__ cxp, float* __restrict__ cyp, float* __restrict__ wp,
    float* __restrict__ hp, float* __restrict__ cp, float* __restrict__ sp,
    float* __restrict__ radp, float* __restrict__ sscp, int* __restrict__ sidx,
    u32* __restrict__ edges, u32* __restrict__ counters,
    float* __restrict__ out) {
#pragma clang fp contract(off)
  cg::grid_group grid = cg::this_grid();
  __shared__ float lx[NB], ly[NB], lr[NB];   // phase2 stage; lx aliases sc in phase1
  __shared__ u32 clist[CLIST_CAP];
  __shared__ float dxL[256 * 25];
  __shared__ float dyL[256 * 25];
  __shared__ float smc[4], smr[4];
  __shared__ u32 ccnt;
  __shared__ u64 keepw[32];
  __shared__ u32 Sw32[64];
  __shared__ int changed;

  int t = threadIdx.x;
  int b = blockIdx.x;
  int wave = t >> 6, lane = t & 63;

  // ================= Phase 1: offset_scale + rank sort + SoA =================
  if (b == 0 && t < 4) counters[t] = 0u;
  float* sc = lx;  // alias: scores live here only during phase 1
  float mc = -1e30f, mr = -1e30f;
  for (int k = t; k < NB; k += 256) {
    float cx = boxes[k * 5 + 0];
    float cy = boxes[k * 5 + 1];
    float w = boxes[k * 5 + 2];
    float h = boxes[k * 5 + 3];
    mc = fmaxf(mc, fmaxf(cx, cy));
    float ww = w * w;
    float hh = h * h;
    mr = fmaxf(mr, sqrtf(ww + hh));
    sc[k] = scores[k];
  }
  for (int off = 32; off > 0; off >>= 1) {
    mc = fmaxf(mc, __shfl_down(mc, off));
    mr = fmaxf(mr, __shfl_down(mr, off));
  }
  if ((t & 63) == 0) { smc[t >> 6] = mc; smr[t >> 6] = mr; }
  __syncthreads();
  mc = fmaxf(fmaxf(smc[0], smc[1]), fmaxf(smc[2], smc[3]));
  mr = fmaxf(fmaxf(smr[0], smr[1]), fmaxf(smr[2], smr[3]));
  float osc = (mc + mr * 0.5f) * 2.0f + 1.0f;

#pragma unroll
  for (int rep = 0; rep < 2; ++rep) {
    int i = b * 8 + rep * 4 + wave;
    float si = sc[i];
    int rank = 0;
#pragma unroll 8
    for (int m = 0; m < NB / 64; ++m) {
      int j = m * 64 + lane;
      float sj = sc[j];
      rank += (int)((sj > si) || (sj == si && j < i));
    }
    for (int off = 32; off > 0; off >>= 1) rank += __shfl_down(rank, off);
    if (lane == 0) {
      float off = (float)labels[i] * osc;
      float cx = boxes[i * 5 + 0] + off;
      float cy = boxes[i * 5 + 1] + off;
      float w = boxes[i * 5 + 2];
      float h = boxes[i * 5 + 3];
      float a = boxes[i * 5 + 4];
      float c = cosf(a);
      float s = sinf(a);
      float ww = w * w;
      float hh = h * h;
      cxp[rank] = cx;
      cyp[rank] = cy;
      wp[rank] = w;
      hp[rank] = h;
      cp[rank] = c;
      sp[rank] = s;
      radp[rank] = 0.5f * sqrtf(ww + hh);
      sscp[rank] = si;
      sidx[rank] = i;
    }
  }
  __threadfence();
  grid.sync();

  // ================= Phase 2: candidates + rotated IoU -> edges ==============
  if (t == 0) ccnt = 0;
  for (int k = t; k < NB; k += 256) {
    lx[k] = cxp[k];
    ly[k] = cyp[k];
    lr[k] = radp[k];
  }
  __syncthreads();
  int i0 = b * 8;
#pragma unroll
  for (int di = 0; di < 8; ++di) {
    int i = i0 + di;
    float ax = lx[i], ay = ly[i], ar = lr[i];
#pragma unroll
    for (int c = 0; c < 8; ++c) {
      int j = c * 256 + t;
      if (j > i) {
        float dx = lx[j] - ax, dy = ly[j] - ay;
        float rr = ar + lr[j] + 1.0f;   // conservative circle pre-test
        if (dx * dx + dy * dy <= rr * rr) {
          u32 s = atomicAdd(&ccnt, 1u);
          if (s < CLIST_CAP) clist[s] = ((u32)i << 16) | (u32)j;
        }
      }
    }
  }
  __syncthreads();
  u32 cnt = ccnt < CLIST_CAP ? ccnt : CLIST_CAP;
  float thr = *thrp;
  float* myDx = &dxL[t * 25];
  float* myDy = &dyL[t * 25];
  for (u32 idx = t; idx < cnt; idx += 256) {
    u32 pk = clist[idx];
    int bi = (int)(pk >> 16);
    int bj = (int)(pk & 0xFFFFu);
    float acx = lx[bi], acy = ly[bi], aw = wp[bi], ah = hp[bi];
    float ac = cp[bi], as_ = sp[bi];
    float bcx = lx[bj], bcy = ly[bj], bw = wp[bj], bh = hp[bj];
    float bc = cp[bj], bs_ = sp[bj];
    const float SX[4] = {-1.f, 1.f, 1.f, -1.f};
    const float SY[4] = {-1.f, -1.f, 1.f, 1.f};
    float axx[4], ayy[4], bxx[4], byy[4];
    float ahw = aw * 0.5f, ahh = ah * 0.5f;
    float bhw = bw * 0.5f, bhh = bh * 0.5f;
#pragma unroll
    for (int q = 0; q < 4; ++q) {
      float dx = SX[q] * ahw, dy = SY[q] * ahh;
      axx[q] = acx + ac * dx - as_ * dy;
      ayy[q] = acy + as_ * dx + ac * dy;
      float ex = SX[q] * bhw, ey = SY[q] * bhh;
      bxx[q] = bcx + bc * ex - bs_ * ey;
      byy[q] = bcy + bs_ * ex + bc * ey;
    }
    float px_[24], py_[24];
    bool mk[24];
#pragma unroll
    for (int q = 0; q < 4; ++q) {
      {
        float axp = axx[q] - bcx, ayp = ayy[q] - bcy;
        float lxx = bc * axp + bs_ * ayp;
        float lyy = bc * ayp - bs_ * axp;
        mk[q] = (fabsf(lxx) <= bhw + 1e-5f) && (fabsf(lyy) <= bhh + 1e-5f);
        px_[q] = axx[q]; py_[q] = ayy[q];
      }
      {
        float axp = bxx[q] - acx, ayp = byy[q] - acy;
        float lxx = ac * axp + as_ * ayp;
        float lyy = ac * ayp - as_ * axp;
        mk[4 + q] = (fabsf(lxx) <= ahw + 1e-5f) && (fabsf(lyy) <= ahh + 1e-5f);
        px_[4 + q] = bxx[q]; py_[4 + q] = byy[q];
      }
    }
#pragma unroll
    for (int e = 0; e < 4; ++e) {
      float rx = axx[(e + 1) & 3] - axx[e];
      float ry = ayy[(e + 1) & 3] - ayy[e];
#pragma unroll
      for (int f = 0; f < 4; ++f) {
        float sx = bxx[(f + 1) & 3] - bxx[f];
        float sy = byy[(f + 1) & 3] - byy[f];
        float denom = rx * sy - ry * sx;
        float qpx = bxx[f] - axx[e];
        float qpy = byy[f] - ayy[e];
        bool dn = fabsf(denom) > 1e-9f;
        float safe = dn ? denom : 1.0f;
        float tt = (qpx * sy - qpy * sx) / safe;
        float uu = (qpx * ry - qpy * rx) / safe;
        bool valid = dn && (tt >= 0.0f) && (tt <= 1.0f) && (uu >= 0.0f) && (uu <= 1.0f);
        int id = 8 + e * 4 + f;
        px_[id] = axx[e] + tt * rx;
        py_[id] = ayy[e] + tt * ry;
        mk[id] = valid;
      }
    }
    int k = 0;
    float sx0 = 0.0f, sy0 = 0.0f;
#pragma unroll
    for (int q = 0; q < 24; ++q) {
      if (mk[q]) { k++; sx0 += px_[q]; sy0 += py_[q]; }
    }
    float kkf = (float)(k > 0 ? k : 1);
    float cxm = sx0 / kkf, cym = sy0 / kkf;
    u64 key[32];
#pragma unroll
    for (int q = 0; q < 24; ++q) {
      float dx = px_[q] - cxm, dy = py_[q] - cym;
      myDx[q] = dx; myDy[q] = dy;
      float sm = fabsf(dx) + fabsf(dy);
      float r = (sm > 0.0f) ? dy / sm : 0.0f;
      float pa;
      if (dx >= 0.0f) pa = r;
      else pa = (__float_as_uint(dy) >> 31) ? (-2.0f - r) : (2.0f - r);
      float ang = mk[q] ? pa : 1e9f;
      u32 ub = __float_as_uint(ang);
      u32 v = (ub & 0x80000000u) ? ~ub : (ub | 0x80000000u);
      key[q] = (((u64)v) << 5) | (u64)q;
    }
#pragma unroll
    for (int q = 24; q < 32; ++q) key[q] = ~0ull;
#pragma unroll
    for (int kk2 = 2; kk2 <= 32; kk2 <<= 1) {
#pragma unroll
      for (int jj = kk2 >> 1; jj > 0; jj >>= 1) {
#pragma unroll
        for (int ii = 0; ii < 32; ++ii) {
          int ll = ii ^ jj;
          if (ll > ii) {
            bool up = ((ii & kk2) == 0);
            u64 ka = key[ii], kb = key[ll];
            bool sw = up ? (ka > kb) : (ka < kb);
            key[ii] = sw ? kb : ka;
            key[ll] = sw ? ka : kb;
          }
        }
      }
    }
    float acc = 0.0f;
    int id0 = (int)(key[0] & 31ull);
    float fx = myDx[id0], fy = myDy[id0];
    float curx = fx, cury = fy;
#pragma unroll
    for (int q = 0; q < 24; ++q) {
      if (q < k - 1) {
        int idn = (int)(key[q + 1] & 31ull);
        float nx = myDx[idn], ny = myDy[idn];
        acc += curx * ny - cury * nx;
        curx = nx; cury = ny;
      } else if (q == k - 1) {
        acc += curx * fy - cury * fx;
      }
    }
    float area = 0.5f * fabsf(acc);
    float inter = (k >= 3) ? area : 0.0f;
    float areaA = aw * ah;
    float areaB = bw * bh;
    float iou = inter / (areaA + areaB - inter + 1e-9f);
    if (iou > thr) {
      u32 e = atomicAdd(&counters[1], 1u);
      if (e < EDGE_CAP) edges[e] = pk;
    }
  }
  __threadfence();
  grid.sync();

  // ============ Phase 3: greedy fixpoint + output scatter (block 0) ==========
  if (b != 0) return;
  u32 ecnt = counters[1];
  if (ecnt > EDGE_CAP) ecnt = EDGE_CAP;
  u32 nl = ecnt < CLIST_CAP ? ecnt : CLIST_CAP;
  for (u32 k = t; k < nl; k += 256) clist[k] = edges[k];  // reuse dead clist
  if (t < 32) keepw[t] = ~0ull;
  __syncthreads();
  for (int iter = 0; iter < 2060; ++iter) {
    if (t < 64) Sw32[t] = 0u;
    if (t == 0) changed = 0;
    __syncthreads();
    for (u32 k = t; k < ecnt; k += 256) {
      u32 pk = (k < CLIST_CAP) ? clist[k] : edges[k];
      int i = (int)(pk >> 16);
      int j = (int)(pk & 0xFFFFu);
      if ((keepw[i >> 6] >> (i & 63)) & 1ull)
        atomicOr(&Sw32[j >> 5], 1u << (j & 31));
    }
    __syncthreads();
    if (t < 32) {
      u64 S = ((u64)Sw32[2 * t]) | (((u64)Sw32[2 * t + 1]) << 32);
      u64 nk = ~S;
      if (nk != keepw[t]) { keepw[t] = nk; changed = 1; }
    }
    __syncthreads();
    int ch = changed;
    __syncthreads();
    if (!ch) break;
  }
  for (int p = t; p < NB; p += 256) {
    int bit = (int)((keepw[p >> 6] >> (p & 63)) & 1ull);
    out[sidx[p]] = bit ? sscp[p] : 0.0f;
  }
}

extern "C" void kernel_launch(void* const* d_in, const int* in_sizes, int n_in,
                              void* d_out, int out_size, void* d_ws, size_t ws_size,
                              hipStream_t stream) {
  const float* boxes = (const float*)d_in[0];
  const float* scores = (const float*)d_in[1];
  const int* labels = (const int*)d_in[2];
  const float* thr = (const float*)d_in[3];
  float* out = (float*)d_out;

  char* base = (char*)d_ws;
  u32* counters = (u32*)base;                       // 4 u32 (pad 256)
  float* arr = (float*)(base + 256);                // 8 x 2048 f32 = 64 KB
  float* cxp = arr + 0 * NB;
  float* cyp = arr + 1 * NB;
  float* wp = arr + 2 * NB;
  float* hp = arr + 3 * NB;
  float* cp = arr + 4 * NB;
  float* sp = arr + 5 * NB;
  float* radp = arr + 6 * NB;
  float* sscp = arr + 7 * NB;
  int* sidx = (int*)(base + 66048);                 // 8 KB
  u32* edges = (u32*)(base + 81920);                // 64 KB

  void* args[] = {(void*)&boxes, (void*)&scores, (void*)&labels, (void*)&thr,
                  (void*)&cxp, (void*)&cyp, (void*)&wp, (void*)&hp,
                  (void*)&cp, (void*)&sp, (void*)&radp, (void*)&sscp,
                  (void*)&sidx, (void*)&edges, (void*)&counters, (void*)&out};
  hipLaunchCooperativeKernel((const void*)nms_all_kernel, dim3(256), dim3(256),
                             args, 0, stream);
}

// Round 10
// 88.229 us; speedup vs baseline: 1.9435x; 1.9435x over previous
//
#include <hip/hip_runtime.h>
#include <cstdint>

typedef unsigned long long u64;
typedef uint32_t u32;

#define NB 2048
#define EDGE_CAP 16384
#define CLIST_CAP 2048

// ---------------------------------------------------------------------------
// Workspace layout (overlap-audited):
//   counters : base +      0 .. 256
//   arr(7xf32): base +   256 .. 57600   (cxp,cyp,wp,hp,cp,sp,sscp)
//   sidx     : base +  57600 .. 65792
//   pxyr     : base +  66048 .. 98816   (float4, 16B aligned)
//   edges    : base + 102400 .. 167936
// ---------------------------------------------------------------------------

// ---------------------------------------------------------------------------
// A: wave-per-box rank sort (512 blocks x 4 waves). Also writes packed
//    float4 (cx, cy, rad, 0) for the register-resident circle sweep.
// ---------------------------------------------------------------------------
__global__ __launch_bounds__(256) void build_kernel(
    const float* __restrict__ boxes, const float* __restrict__ scores,
    const int* __restrict__ labels,
    float* __restrict__ cxp, float* __restrict__ cyp, float* __restrict__ wp,
    float* __restrict__ hp, float* __restrict__ cp, float* __restrict__ sp,
    float4* __restrict__ pxyr, float* __restrict__ sscp, int* __restrict__ sidx,
    u32* __restrict__ counters) {
#pragma clang fp contract(off)
  __shared__ float sc[NB];
  __shared__ float smc[4], smr[4];
  int t = threadIdx.x;
  if (blockIdx.x == 0 && t < 4) counters[t] = 0u;
  float mc = -1e30f, mr = -1e30f;
  for (int k = t; k < NB; k += 256) {
    float cx = boxes[k * 5 + 0];
    float cy = boxes[k * 5 + 1];
    float w = boxes[k * 5 + 2];
    float h = boxes[k * 5 + 3];
    mc = fmaxf(mc, fmaxf(cx, cy));
    float ww = w * w;
    float hh = h * h;
    mr = fmaxf(mr, sqrtf(ww + hh));
    sc[k] = scores[k];
  }
  for (int off = 32; off > 0; off >>= 1) {
    mc = fmaxf(mc, __shfl_down(mc, off));
    mr = fmaxf(mr, __shfl_down(mr, off));
  }
  if ((t & 63) == 0) { smc[t >> 6] = mc; smr[t >> 6] = mr; }
  __syncthreads();
  mc = fmaxf(fmaxf(smc[0], smc[1]), fmaxf(smc[2], smc[3]));
  mr = fmaxf(fmaxf(smr[0], smr[1]), fmaxf(smr[2], smr[3]));
  float osc = (mc + mr * 0.5f) * 2.0f + 1.0f;

  int wave = t >> 6, lane = t & 63;
  int i = blockIdx.x * 4 + wave;
  float si = sc[i];
  int rank = 0;
#pragma unroll 8
  for (int m = 0; m < NB / 64; ++m) {
    int j = m * 64 + lane;
    float sj = sc[j];
    rank += (int)((sj > si) || (sj == si && j < i));
  }
  for (int off = 32; off > 0; off >>= 1) rank += __shfl_down(rank, off);
  if (lane == 0) {
    float off = (float)labels[i] * osc;
    float cx = boxes[i * 5 + 0] + off;
    float cy = boxes[i * 5 + 1] + off;
    float w = boxes[i * 5 + 2];
    float h = boxes[i * 5 + 3];
    float a = boxes[i * 5 + 4];
    float c = cosf(a);
    float s = sinf(a);
    float ww = w * w;
    float hh = h * h;
    float rad = 0.5f * sqrtf(ww + hh);
    cxp[rank] = cx;
    cyp[rank] = cy;
    wp[rank] = w;
    hp[rank] = h;
    cp[rank] = c;
    sp[rank] = s;
    pxyr[rank] = make_float4(cx, cy, rad, 0.0f);
    sscp[rank] = si;
    sidx[rank] = i;
  }
}

// ---------------------------------------------------------------------------
// B+C+D fused, 512 blocks x 4 rows. Circle sweep entirely in registers
// (8 coalesced float4 j-loads per thread, broadcast i-loads); candidates ->
// LDS clist; heavy rotated-IoU (pseudo-angle + key-only register bitonic,
// dx/dy in conflict-free per-lane LDS slices); edges -> global. Last block
// (device-scope election, release/acquire fences) runs the greedy fixpoint
// + output scatter.
// ---------------------------------------------------------------------------
__global__ __launch_bounds__(256) void candgeom_greedy_kernel(
    const float* __restrict__ cxp, const float* __restrict__ cyp,
    const float* __restrict__ wp, const float* __restrict__ hp,
    const float* __restrict__ cp, const float* __restrict__ sp,
    const float4* __restrict__ pxyr, const float* __restrict__ thrp,
    const float* __restrict__ sscp, const int* __restrict__ sidx,
    u32* __restrict__ edges, u32* __restrict__ counters,
    float* __restrict__ out) {
#pragma clang fp contract(off)
  __shared__ u32 clist[CLIST_CAP];
  __shared__ float dxL[256 * 25];
  __shared__ float dyL[256 * 25];
  __shared__ u32 ccnt;
  __shared__ int is_last;
  __shared__ u64 keepw[32];
  __shared__ u32 Sw32[64];
  __shared__ int changed;
  int t = threadIdx.x;
  if (t == 0) ccnt = 0;
  // register-resident j columns: j = c*256 + t
  float jx[8], jy[8], jr[8];
#pragma unroll
  for (int c = 0; c < 8; ++c) {
    float4 v = pxyr[c * 256 + t];
    jx[c] = v.x; jy[c] = v.y; jr[c] = v.z;
  }
  __syncthreads();   // ccnt initialized
  int i0 = blockIdx.x * 4;
#pragma unroll
  for (int di = 0; di < 4; ++di) {
    int i = i0 + di;
    float4 pi = pxyr[i];            // same-address broadcast load
    float ax = pi.x, ay = pi.y, ar = pi.z;
#pragma unroll
    for (int c = 0; c < 8; ++c) {
      int j = c * 256 + t;
      if (j > i) {
        float dx = jx[c] - ax, dy = jy[c] - ay;
        float rr = ar + jr[c] + 1.0f;   // conservative circle pre-test
        if (dx * dx + dy * dy <= rr * rr) {
          u32 s = atomicAdd(&ccnt, 1u);
          if (s < CLIST_CAP) clist[s] = ((u32)i << 16) | (u32)j;
        }
      }
    }
  }
  __syncthreads();
  u32 cnt = ccnt < CLIST_CAP ? ccnt : CLIST_CAP;
  float thr = *thrp;
  float* myDx = &dxL[t * 25];
  float* myDy = &dyL[t * 25];
  for (u32 idx = t; idx < cnt; idx += 256) {
    u32 pk = clist[idx];
    int bi = (int)(pk >> 16);
    int bj = (int)(pk & 0xFFFFu);
    float acx = cxp[bi], acy = cyp[bi], aw = wp[bi], ah = hp[bi];
    float ac = cp[bi], as_ = sp[bi];
    float bcx = cxp[bj], bcy = cyp[bj], bw = wp[bj], bh = hp[bj];
    float bc = cp[bj], bs_ = sp[bj];
    const float SX[4] = {-1.f, 1.f, 1.f, -1.f};
    const float SY[4] = {-1.f, -1.f, 1.f, 1.f};
    float axx[4], ayy[4], bxx[4], byy[4];
    float ahw = aw * 0.5f, ahh = ah * 0.5f;
    float bhw = bw * 0.5f, bhh = bh * 0.5f;
#pragma unroll
    for (int q = 0; q < 4; ++q) {
      float dx = SX[q] * ahw, dy = SY[q] * ahh;
      axx[q] = acx + ac * dx - as_ * dy;
      ayy[q] = acy + as_ * dx + ac * dy;
      float ex = SX[q] * bhw, ey = SY[q] * bhh;
      bxx[q] = bcx + bc * ex - bs_ * ey;
      byy[q] = bcy + bs_ * ex + bc * ey;
    }
    float px_[24], py_[24];
    bool mk[24];
#pragma unroll
    for (int q = 0; q < 4; ++q) {
      {
        float axp = axx[q] - bcx, ayp = ayy[q] - bcy;
        float lxx = bc * axp + bs_ * ayp;
        float lyy = bc * ayp - bs_ * axp;
        mk[q] = (fabsf(lxx) <= bhw + 1e-5f) && (fabsf(lyy) <= bhh + 1e-5f);
        px_[q] = axx[q]; py_[q] = ayy[q];
      }
      {
        float axp = bxx[q] - acx, ayp = byy[q] - acy;
        float lxx = ac * axp + as_ * ayp;
        float lyy = ac * ayp - as_ * axp;
        mk[4 + q] = (fabsf(lxx) <= ahw + 1e-5f) && (fabsf(lyy) <= ahh + 1e-5f);
        px_[4 + q] = bxx[q]; py_[4 + q] = byy[q];
      }
    }
#pragma unroll
    for (int e = 0; e < 4; ++e) {
      float rx = axx[(e + 1) & 3] - axx[e];
      float ry = ayy[(e + 1) & 3] - ayy[e];
#pragma unroll
      for (int f = 0; f < 4; ++f) {
        float sx = bxx[(f + 1) & 3] - bxx[f];
        float sy = byy[(f + 1) & 3] - byy[f];
        float denom = rx * sy - ry * sx;
        float qpx = bxx[f] - axx[e];
        float qpy = byy[f] - ayy[e];
        bool dn = fabsf(denom) > 1e-9f;
        float safe = dn ? denom : 1.0f;
        float tt = (qpx * sy - qpy * sx) / safe;
        float uu = (qpx * ry - qpy * rx) / safe;
        bool valid = dn && (tt >= 0.0f) && (tt <= 1.0f) && (uu >= 0.0f) && (uu <= 1.0f);
        int id = 8 + e * 4 + f;
        px_[id] = axx[e] + tt * rx;
        py_[id] = ayy[e] + tt * ry;
        mk[id] = valid;
      }
    }
    int k = 0;
    float sx0 = 0.0f, sy0 = 0.0f;
#pragma unroll
    for (int q = 0; q < 24; ++q) {
      if (mk[q]) { k++; sx0 += px_[q]; sy0 += py_[q]; }
    }
    float kkf = (float)(k > 0 ? k : 1);
    float cxm = sx0 / kkf, cym = sy0 / kkf;
    u64 key[32];
#pragma unroll
    for (int q = 0; q < 24; ++q) {
      float dx = px_[q] - cxm, dy = py_[q] - cym;
      myDx[q] = dx; myDy[q] = dy;
      float sm = fabsf(dx) + fabsf(dy);
      float r = (sm > 0.0f) ? dy / sm : 0.0f;
      float pa;
      if (dx >= 0.0f) pa = r;
      else pa = (__float_as_uint(dy) >> 31) ? (-2.0f - r) : (2.0f - r);
      float ang = mk[q] ? pa : 1e9f;
      u32 ub = __float_as_uint(ang);
      u32 v = (ub & 0x80000000u) ? ~ub : (ub | 0x80000000u);
      key[q] = (((u64)v) << 5) | (u64)q;
    }
#pragma unroll
    for (int q = 24; q < 32; ++q) key[q] = ~0ull;
#pragma unroll
    for (int kk2 = 2; kk2 <= 32; kk2 <<= 1) {
#pragma unroll
      for (int jj = kk2 >> 1; jj > 0; jj >>= 1) {
#pragma unroll
        for (int ii = 0; ii < 32; ++ii) {
          int ll = ii ^ jj;
          if (ll > ii) {
            bool up = ((ii & kk2) == 0);
            u64 ka = key[ii], kb = key[ll];
            bool sw = up ? (ka > kb) : (ka < kb);
            key[ii] = sw ? kb : ka;
            key[ll] = sw ? ka : kb;
          }
        }
      }
    }
    float acc = 0.0f;
    int id0 = (int)(key[0] & 31ull);
    float fx = myDx[id0], fy = myDy[id0];
    float curx = fx, cury = fy;
#pragma unroll
    for (int q = 0; q < 24; ++q) {
      if (q < k - 1) {
        int idn = (int)(key[q + 1] & 31ull);
        float nx = myDx[idn], ny = myDy[idn];
        acc += curx * ny - cury * nx;
        curx = nx; cury = ny;
      } else if (q == k - 1) {
        acc += curx * fy - cury * fx;
      }
    }
    float area = 0.5f * fabsf(acc);
    float inter = (k >= 3) ? area : 0.0f;
    float areaA = aw * ah;
    float areaB = bw * bh;
    float iou = inter / (areaA + areaB - inter + 1e-9f);
    if (iou > thr) {
      u32 e = atomicAdd(&counters[1], 1u);
      if (e < EDGE_CAP) edges[e] = pk;
    }
  }
  // ---- publish this block's edges; elect the last-finishing block ----
  __syncthreads();
  if (t == 0) {
    __threadfence();             // release: edges visible device-wide
    u32 old = atomicAdd(&counters[2], 1u);
    is_last = (old == (u32)(gridDim.x - 1)) ? 1 : 0;
  }
  __syncthreads();
  if (!is_last) return;
  __threadfence();               // acquire
  __syncthreads();
  // ---- greedy fixpoint (antitone F => exact sequential-greedy fixpoint) ----
  u32 ecnt = counters[1];
  if (ecnt > EDGE_CAP) ecnt = EDGE_CAP;
  u32 nl = ecnt < CLIST_CAP ? ecnt : CLIST_CAP;
  for (u32 k = t; k < nl; k += 256) clist[k] = edges[k];  // reuse dead clist
  if (t < 32) keepw[t] = ~0ull;
  __syncthreads();
  for (int iter = 0; iter < 2060; ++iter) {
    if (t < 64) Sw32[t] = 0u;
    if (t == 0) changed = 0;
    __syncthreads();
    for (u32 k = t; k < ecnt; k += 256) {
      u32 pk = (k < CLIST_CAP) ? clist[k] : edges[k];
      int i = (int)(pk >> 16);
      int j = (int)(pk & 0xFFFFu);
      if ((keepw[i >> 6] >> (i & 63)) & 1ull)
        atomicOr(&Sw32[j >> 5], 1u << (j & 31));
    }
    __syncthreads();
    if (t < 32) {
      u64 S = ((u64)Sw32[2 * t]) | (((u64)Sw32[2 * t + 1]) << 32);
      u64 nk = ~S;
      if (nk != keepw[t]) { keepw[t] = nk; changed = 1; }
    }
    __syncthreads();
    int ch = changed;
    __syncthreads();
    if (!ch) break;
  }
  // ---- output scatter ----
  for (int p = t; p < NB; p += 256) {
    int bit = (int)((keepw[p >> 6] >> (p & 63)) & 1ull);
    out[sidx[p]] = bit ? sscp[p] : 0.0f;
  }
}

extern "C" void kernel_launch(void* const* d_in, const int* in_sizes, int n_in,
                              void* d_out, int out_size, void* d_ws, size_t ws_size,
                              hipStream_t stream) {
  const float* boxes = (const float*)d_in[0];
  const float* scores = (const float*)d_in[1];
  const int* labels = (const int*)d_in[2];
  const float* thr = (const float*)d_in[3];
  float* out = (float*)d_out;

  char* base = (char*)d_ws;
  u32* counters = (u32*)base;                       // base+0     .. 256
  float* arr = (float*)(base + 256);                // base+256   .. 57600
  float* cxp = arr + 0 * NB;
  float* cyp = arr + 1 * NB;
  float* wp = arr + 2 * NB;
  float* hp = arr + 3 * NB;
  float* cp = arr + 4 * NB;
  float* sp = arr + 5 * NB;
  float* sscp = arr + 6 * NB;
  int* sidx = (int*)(base + 57600);                 // base+57600 .. 65792
  float4* pxyr = (float4*)(base + 66048);           // base+66048 .. 98816
  u32* edges = (u32*)(base + 102400);               // base+102400.. 167936

  build_kernel<<<512, 256, 0, stream>>>(boxes, scores, labels, cxp, cyp, wp, hp,
                                        cp, sp, pxyr, sscp, sidx, counters);
  candgeom_greedy_kernel<<<512, 256, 0, stream>>>(cxp, cyp, wp, hp, cp, sp,
                                                  pxyr, thr, sscp, sidx,
                                                  edges, counters, out);
}